// Round 7
// baseline (148.106 us; speedup 1.0000x reference)
//
#include <hip/hip_runtime.h>
#include <hip/hip_bf16.h>
#include <stdint.h>

typedef float f32x4 __attribute__((ext_vector_type(4)));
typedef short short4v __attribute__((ext_vector_type(4)));
typedef short short8 __attribute__((ext_vector_type(8)));
typedef __bf16 bf16x8 __attribute__((ext_vector_type(8)));

#define D_MODEL 512
#define MAX_LEN 1024
#define M_TOTAL 65536

static __device__ __forceinline__ short f2bf(float f) {
  union { __hip_bfloat16 h; short s; } u;
  u.h = __float2bfloat16(f);
  return u.s;
}

static __device__ __forceinline__ bf16x8 as_bf16x8(short8 s) {
  union { short8 s; bf16x8 b; } u;
  u.s = s;
  return u.b;
}

// async global->LDS, 16B per lane. LDS dest must be wave-uniform base + lane*16.
static __device__ __forceinline__ void gload_lds16(const void* g, void* l) {
  __builtin_amdgcn_global_load_lds(
      (const __attribute__((address_space(1))) uint32_t*)(uintptr_t)g,
      (__attribute__((address_space(3))) uint32_t*)(uint32_t)(uintptr_t)l,
      16, 0, 0);
}

static __device__ __forceinline__ void mfma_bf16(f32x4& c, short8 a, short8 b) {
  asm("v_mfma_f32_16x16x32_bf16 %0, %1, %2, %0" : "+v"(c) : "v"(a), "v"(b));
}

// ---------------- prep: W [1024][512] f32 -> WtopT / WbotT [512][512] bf16 ([n][k]) ----
__global__ __launch_bounds__(256) void prep_w_kernel(const float* __restrict__ W,
                                                     short* __restrict__ WtT,
                                                     short* __restrict__ WbT) {
  __shared__ float tile[64][65];
  const int t = threadIdx.x;
  const int nt = blockIdx.x * 64;   // n tile in [0,512)
  const int kt = blockIdx.y * 64;   // k tile in [0,1024)
  const int c = t & 63;
  const int r0 = t >> 6;
#pragma unroll
  for (int r = r0; r < 64; r += 4)
    tile[r][c] = W[(size_t)(kt + r) * D_MODEL + nt + c];
  __syncthreads();
  short* dst = (kt < D_MODEL) ? WtT : WbT;
  const int kb = kt & (D_MODEL - 1);
#pragma unroll
  for (int n = r0; n < 64; n += 4)
    dst[(size_t)(nt + n) * D_MODEL + kb + c] = f2bf(tile[c][n]);
}

// ---------------- prep: encoding [1024][512] f32 -> bf16 (row-major) -------------------
__global__ __launch_bounds__(256) void prep_enc_kernel(const float* __restrict__ enc,
                                                       short* __restrict__ encb) {
  const int i = (blockIdx.x * 256 + threadIdx.x) * 4;
  float4 v = *reinterpret_cast<const float4*>(enc + i);
  short4 r = make_short4(f2bf(v.x), f2bf(v.y), f2bf(v.z), f2bf(v.w));
  *reinterpret_cast<short4*>(encb + i) = r;
}

// ---------------- GEMM1: encW[1024][512] = enc_bf16 @ WtopT^T (fp32 out) ---------------
__global__ __launch_bounds__(256) void gemm_encw_kernel(const short* __restrict__ A,
                                                        const short* __restrict__ BT,
                                                        float* __restrict__ C) {
  __shared__ short As[128 * 32];
  __shared__ short Bs[128 * 32];
  const int t = threadIdx.x;
  const int lane = t & 63;
  const int wave = t >> 6;
  const int wm = wave >> 1, wn = wave & 1;
  const int m0 = blockIdx.y * 128, n0 = blockIdx.x * 128;
  const int koff = (t & 3) * 8;
  const int rr = t >> 2;
  const int l15 = lane & 15, lk = (lane >> 4) * 8;
  f32x4 acc[4][4] = {};
  for (int kt = 0; kt < D_MODEL; kt += 32) {
    __syncthreads();
    gload_lds16(A + (size_t)(m0 + rr) * D_MODEL + kt + koff, (char*)As + t * 16);
    gload_lds16(A + (size_t)(m0 + 64 + rr) * D_MODEL + kt + koff, (char*)As + 4096 + t * 16);
    gload_lds16(BT + (size_t)(n0 + rr) * D_MODEL + kt + koff, (char*)Bs + t * 16);
    gload_lds16(BT + (size_t)(n0 + 64 + rr) * D_MODEL + kt + koff, (char*)Bs + 4096 + t * 16);
    __syncthreads();
    short8 af[4], bfr[4];
#pragma unroll
    for (int mi = 0; mi < 4; ++mi)
      af[mi] = *reinterpret_cast<const short8*>(&As[(wm * 64 + mi * 16 + l15) * 32 + lk]);
#pragma unroll
    for (int ni = 0; ni < 4; ++ni)
      bfr[ni] = *reinterpret_cast<const short8*>(&Bs[(wn * 64 + ni * 16 + l15) * 32 + lk]);
#pragma unroll
    for (int mi = 0; mi < 4; ++mi)
#pragma unroll
      for (int ni = 0; ni < 4; ++ni)
        mfma_bf16(acc[mi][ni], af[mi], bfr[ni]);
  }
#pragma unroll
  for (int mi = 0; mi < 4; ++mi)
#pragma unroll
    for (int r = 0; r < 4; ++r) {
      const int row = m0 + wm * 64 + mi * 16 + (lane >> 4) * 4 + r;
#pragma unroll
      for (int ni = 0; ni < 4; ++ni) {
        const int col = n0 + wn * 64 + ni * 16 + l15;
        C[(size_t)row * D_MODEL + col] = acc[mi][ni][r];
      }
    }
}

// ---------------- GEMM2: out = latent @ WbotT^T + encW[dfn] + encW[dfa] + b ------------
// BM=BN=128, BK=32, double-buffered + issue-early, 32KB LDS -> 4 blocks/CU
// (launch_bounds(256,4)): 4 independent barrier-groups per SIMD fill each other's
// latency bubbles. LDS rows are 64B (4x16B slots); swizzle s' = s ^ ((row>>1)&3)
// spreads 16-lane frag reads over all 8 bank-quads. Same involution applied on the
// pre-swizzled gload source (B), the ds_write (A), and both read sides.
__global__ __launch_bounds__(256, 4) void gemm_main_kernel(
    const float* __restrict__ latent,   // [65536][512] f32
    const short* __restrict__ BT,       // WbotT [512][512] bf16 ([n][k])
    const float* __restrict__ encW,     // [1024][512] f32
    const int* __restrict__ dfn,
    const int* __restrict__ dfa,
    const float* __restrict__ bias,     // [512]
    float* __restrict__ out) {          // [65536][512] f32
  __shared__ alignas(16) short As0[128 * 32];
  __shared__ alignas(16) short As1[128 * 32];
  __shared__ alignas(16) short Bs0[128 * 32];
  __shared__ alignas(16) short Bs1[128 * 32];
  const int t = threadIdx.x;
  const int lane = t & 63;
  const int wave = t >> 6;
  const int wm = wave >> 1, wn = wave & 1;

  // XCD-chunked mapping: xcd = bid&7 owns m-panels [xcd*64, xcd*64+64);
  // 4 n-blocks of each m-panel consecutive -> same-XCD L2 reuse of A.
  const int bid = blockIdx.x;
  const int slot = bid >> 3;
  const int mblk = (bid & 7) * 64 + (slot >> 2);
  const int nblk = slot & 3;
  const int m0 = mblk * 128, n0 = nblk * 128;

  // B staging: chunk c in {0,1}: row r = c*64 + (t>>2), 16B slot s = t&3;
  // global source pre-swizzled: LDS[r][s] = global[r][s ^ ((r>>1)&3)].
  const int rB = t >> 2;
  const int sgB = (t & 3) ^ ((t >> 3) & 3);   // (c*64>>1)%4==0, so same for both chunks
  // A staging (coalesced): step j in 0..3: row r = j*32 + (t>>3), f32 cols (t&7)*4..+4.
  const int rA8 = t >> 3;                     // row within 32-row group
  const int sA = (t & 7) >> 1;                // 16B slot
  const int hA = t & 1;                       // 8B half
  const int swA = sA ^ ((rA8 >> 1) & 3);      // (j*32>>1)%4==0, thread-constant
  const int wbyteA = swA * 16 + hA * 8;

  const int l15 = lane & 15;
  const int lsl = lane >> 4;   // k sub-slot 0..3

  const float* aBase = latent + (size_t)(m0 + rA8) * D_MODEL + (t & 7) * 4;
  const short* bptr[2];
#pragma unroll
  for (int c = 0; c < 2; ++c)
    bptr[c] = BT + (size_t)(n0 + c * 64 + rB) * D_MODEL + sgB * 8;

  f32x4 acc[4][4] = {};
  f32x4 av[4];

  // ---- helpers (macros keep every LDS address compile-time static) ----
#define STAGE_B(KO, BDST)                                                   \
  {                                                                         \
    _Pragma("unroll") for (int c = 0; c < 2; ++c)                           \
        gload_lds16(bptr[c] + (KO), (char*)(BDST) + c * 4096 + t * 16);     \
  }
#define LOAD_A(KO)                                                          \
  {                                                                         \
    _Pragma("unroll") for (int j = 0; j < 4; ++j)                           \
        av[j] = *reinterpret_cast<const f32x4*>(aBase + (size_t)j * 32 * D_MODEL + (KO)); \
  }
#define WRITE_A(ADST)                                                       \
  {                                                                         \
    _Pragma("unroll") for (int j = 0; j < 4; ++j) {                         \
      short4v h;                                                            \
      h[0] = f2bf(av[j][0]); h[1] = f2bf(av[j][1]);                         \
      h[2] = f2bf(av[j][2]); h[3] = f2bf(av[j][3]);                         \
      *reinterpret_cast<short4v*>((char*)(ADST) + (j * 32 + rA8) * 64 + wbyteA) = h; \
    }                                                                       \
  }
#define COMPUTE(ASRC, BSRC)                                                 \
  {                                                                         \
    bf16x8 af[4], bfv[4];                                                   \
    _Pragma("unroll") for (int mi = 0; mi < 4; ++mi) {                      \
      const int r = wm * 64 + mi * 16 + l15;                                \
      const int s = lsl ^ ((r >> 1) & 3);                                   \
      af[mi] = as_bf16x8(                                                   \
          *reinterpret_cast<const short8*>((char*)(ASRC) + r * 64 + s * 16)); \
    }                                                                       \
    _Pragma("unroll") for (int ni = 0; ni < 4; ++ni) {                      \
      const int r = wn * 64 + ni * 16 + l15;                                \
      const int s = lsl ^ ((r >> 1) & 3);                                   \
      bfv[ni] = as_bf16x8(                                                  \
          *reinterpret_cast<const short8*>((char*)(BSRC) + r * 64 + s * 16)); \
    }                                                                       \
    _Pragma("unroll") for (int mi = 0; mi < 4; ++mi)                        \
        _Pragma("unroll") for (int ni = 0; ni < 4; ++ni)                    \
            acc[mi][ni] = __builtin_amdgcn_mfma_f32_16x16x32_bf16(          \
                af[mi], bfv[ni], acc[mi][ni], 0, 0, 0);                     \
  }

  // ---- prologue: tile 0 into buffer 0 ----
  STAGE_B(0, Bs0);
  LOAD_A(0);
  WRITE_A(As0);
  __syncthreads();

  // ---- main loop: 16 K-steps as 8 even/odd pairs (static buffers) ----
#pragma unroll
  for (int tt = 0; tt < 8; ++tt) {
    // even step 2tt: compute buf0, stage tile 2tt+1 into buf1
    {
      const int ko = (2 * tt + 1) * 32;
      STAGE_B(ko, Bs1);
      LOAD_A(ko);
      COMPUTE(As0, Bs0);
      WRITE_A(As1);
      __syncthreads();
    }
    // odd step 2tt+1: compute buf1, stage tile 2tt+2 into buf0 (if any)
    {
      if (tt < 7) {
        const int ko = (2 * tt + 2) * 32;
        STAGE_B(ko, Bs0);
        LOAD_A(ko);
      }
      COMPUTE(As1, Bs1);
      if (tt < 7) WRITE_A(As0);
      __syncthreads();
    }
  }

  // epilogue: fused gather of encW rows (2 MB, L2/L3-resident) + bias
#pragma unroll
  for (int mi = 0; mi < 4; ++mi) {
#pragma unroll
    for (int r = 0; r < 4; ++r) {
      const int row = m0 + wm * 64 + mi * 16 + lsl * 4 + r;
      const int d1 = dfn[row];
      const int d2 = dfa[row];
      const float* e1 = encW + (size_t)d1 * D_MODEL;
      const float* e2 = encW + (size_t)d2 * D_MODEL;
      const size_t ro = (size_t)row * D_MODEL;
#pragma unroll
      for (int ni = 0; ni < 4; ++ni) {
        const int col = n0 + wn * 64 + ni * 16 + l15;
        out[ro + col] = acc[mi][ni][r] + e1[col] + e2[col] + bias[col];
      }
    }
  }
#undef STAGE_B
#undef LOAD_A
#undef WRITE_A
#undef COMPUTE
}

extern "C" void kernel_launch(void* const* d_in, const int* in_sizes, int n_in,
                              void* d_out, int out_size, void* d_ws, size_t ws_size,
                              hipStream_t stream) {
  const int* dfn = (const int*)d_in[0];
  const int* dfa = (const int*)d_in[1];
  const float* latent = (const float*)d_in[2];
  const float* enc = (const float*)d_in[3];
  const float* W = (const float*)d_in[4];
  const float* bias = (const float*)d_in[5];
  float* out = (float*)d_out;

  // workspace layout (4 MB total)
  char* ws = (char*)d_ws;
  short* WtT  = (short*)(ws);                       // 512KB  [512][512] bf16
  short* WbT  = (short*)(ws + 512 * 1024);          // 512KB  [512][512] bf16
  short* encb = (short*)(ws + 1024 * 1024);         // 1MB    [1024][512] bf16
  float* encW = (float*)(ws + 2 * 1024 * 1024);     // 2MB    [1024][512] f32

  hipLaunchKernelGGL(prep_w_kernel, dim3(8, 16), dim3(256), 0, stream, W, WtT, WbT);
  hipLaunchKernelGGL(prep_enc_kernel, dim3(512), dim3(256), 0, stream, enc, encb);
  hipLaunchKernelGGL(gemm_encw_kernel, dim3(4, 8), dim3(256), 0, stream, encb, WtT, encW);
  hipLaunchKernelGGL(gemm_main_kernel, dim3(2048), dim3(256), 0, stream,
                     latent, WbT, encW, dfn, dfa, bias, out);
}

// Round 8
// 110.352 us; speedup vs baseline: 1.3421x; 1.3421x over previous
//
#include <hip/hip_runtime.h>
#include <hip/hip_bf16.h>
#include <stdint.h>

typedef float f32x4 __attribute__((ext_vector_type(4)));
typedef short short4v __attribute__((ext_vector_type(4)));
typedef short short8 __attribute__((ext_vector_type(8)));
typedef __bf16 bf16x8 __attribute__((ext_vector_type(8)));

#define D_MODEL 512
#define MAX_LEN 1024
#define M_TOTAL 65536

static __device__ __forceinline__ short f2bf(float f) {
  union { __hip_bfloat16 h; short s; } u;
  u.h = __float2bfloat16(f);
  return u.s;
}

static __device__ __forceinline__ bf16x8 as_bf16x8(short8 s) {
  union { short8 s; bf16x8 b; } u;
  u.s = s;
  return u.b;
}

// async global->LDS, 16B per lane. LDS dest must be wave-uniform base + lane*16.
static __device__ __forceinline__ void gload_lds16(const void* g, void* l) {
  __builtin_amdgcn_global_load_lds(
      (const __attribute__((address_space(1))) uint32_t*)(uintptr_t)g,
      (__attribute__((address_space(3))) uint32_t*)(uint32_t)(uintptr_t)l,
      16, 0, 0);
}

static __device__ __forceinline__ void mfma_bf16(f32x4& c, short8 a, short8 b) {
  asm("v_mfma_f32_16x16x32_bf16 %0, %1, %2, %0" : "+v"(c) : "v"(a), "v"(b));
}

// ---------------- prep: W [1024][512] f32 -> WtopT / WbotT [512][512] bf16 ([n][k]) ----
__global__ __launch_bounds__(256) void prep_w_kernel(const float* __restrict__ W,
                                                     short* __restrict__ WtT,
                                                     short* __restrict__ WbT) {
  __shared__ float tile[64][65];
  const int t = threadIdx.x;
  const int nt = blockIdx.x * 64;   // n tile in [0,512)
  const int kt = blockIdx.y * 64;   // k tile in [0,1024)
  const int c = t & 63;
  const int r0 = t >> 6;
#pragma unroll
  for (int r = r0; r < 64; r += 4)
    tile[r][c] = W[(size_t)(kt + r) * D_MODEL + nt + c];
  __syncthreads();
  short* dst = (kt < D_MODEL) ? WtT : WbT;
  const int kb = kt & (D_MODEL - 1);
#pragma unroll
  for (int n = r0; n < 64; n += 4)
    dst[(size_t)(nt + n) * D_MODEL + kb + c] = f2bf(tile[c][n]);
}

// ---------------- prep: encoding [1024][512] f32 -> bf16 (row-major) -------------------
__global__ __launch_bounds__(256) void prep_enc_kernel(const float* __restrict__ enc,
                                                       short* __restrict__ encb) {
  const int i = (blockIdx.x * 256 + threadIdx.x) * 4;
  float4 v = *reinterpret_cast<const float4*>(enc + i);
  short4 r = make_short4(f2bf(v.x), f2bf(v.y), f2bf(v.z), f2bf(v.w));
  *reinterpret_cast<short4*>(encb + i) = r;
}

// ---------------- GEMM1: encW[1024][512] = enc_bf16 @ WtopT^T (fp32 out) ---------------
__global__ __launch_bounds__(256) void gemm_encw_kernel(const short* __restrict__ A,
                                                        const short* __restrict__ BT,
                                                        float* __restrict__ C) {
  __shared__ short As[128 * 32];
  __shared__ short Bs[128 * 32];
  const int t = threadIdx.x;
  const int lane = t & 63;
  const int wave = t >> 6;
  const int wm = wave >> 1, wn = wave & 1;
  const int m0 = blockIdx.y * 128, n0 = blockIdx.x * 128;
  const int koff = (t & 3) * 8;
  const int rr = t >> 2;
  const int l15 = lane & 15, lk = (lane >> 4) * 8;
  f32x4 acc[4][4] = {};
  for (int kt = 0; kt < D_MODEL; kt += 32) {
    __syncthreads();
    gload_lds16(A + (size_t)(m0 + rr) * D_MODEL + kt + koff, (char*)As + t * 16);
    gload_lds16(A + (size_t)(m0 + 64 + rr) * D_MODEL + kt + koff, (char*)As + 4096 + t * 16);
    gload_lds16(BT + (size_t)(n0 + rr) * D_MODEL + kt + koff, (char*)Bs + t * 16);
    gload_lds16(BT + (size_t)(n0 + 64 + rr) * D_MODEL + kt + koff, (char*)Bs + 4096 + t * 16);
    __syncthreads();
    short8 af[4], bfr[4];
#pragma unroll
    for (int mi = 0; mi < 4; ++mi)
      af[mi] = *reinterpret_cast<const short8*>(&As[(wm * 64 + mi * 16 + l15) * 32 + lk]);
#pragma unroll
    for (int ni = 0; ni < 4; ++ni)
      bfr[ni] = *reinterpret_cast<const short8*>(&Bs[(wn * 64 + ni * 16 + l15) * 32 + lk]);
#pragma unroll
    for (int mi = 0; mi < 4; ++mi)
#pragma unroll
      for (int ni = 0; ni < 4; ++ni)
        mfma_bf16(acc[mi][ni], af[mi], bfr[ni]);
  }
#pragma unroll
  for (int mi = 0; mi < 4; ++mi)
#pragma unroll
    for (int r = 0; r < 4; ++r) {
      const int row = m0 + wm * 64 + mi * 16 + (lane >> 4) * 4 + r;
#pragma unroll
      for (int ni = 0; ni < 4; ++ni) {
        const int col = n0 + wn * 64 + ni * 16 + l15;
        C[(size_t)row * D_MODEL + col] = acc[mi][ni][r];
      }
    }
}

// ---------------- GEMM2: out = latent @ WbotT^T + encW[dfn] + encW[dfa] + b ------------
// r6 base (BM=BN=128, BK=64, XOR-swizzled LDS, XCD-chunked map, double-buffered LDS)
// + 2-step-deep A register prefetch (T14): at step t issue global loads for tile t+2;
// WRITE_A at step t converts tile t+1 (loaded a full step ago -> HBM latency covered).
// Plain global->reg loads are NOT drained by __syncthreads, so the prefetch distance
// survives the barrier; only B's gload_lds (L2-resident, short latency) is drained.
__global__ __launch_bounds__(256, 2) void gemm_main_kernel(
    const float* __restrict__ latent,   // [65536][512] f32
    const short* __restrict__ BT,       // WbotT [512][512] bf16 ([n][k])
    const float* __restrict__ encW,     // [1024][512] f32
    const int* __restrict__ dfn,
    const int* __restrict__ dfa,
    const float* __restrict__ bias,     // [512]
    float* __restrict__ out) {          // [65536][512] f32
  __shared__ alignas(16) short As0[128 * 64];
  __shared__ alignas(16) short As1[128 * 64];
  __shared__ alignas(16) short Bs0[128 * 64];
  __shared__ alignas(16) short Bs1[128 * 64];
  const int t = threadIdx.x;
  const int lane = t & 63;
  const int wave = t >> 6;
  const int wm = wave >> 1, wn = wave & 1;

  // XCD-chunked mapping: xcd = bid&7 owns m-panels [xcd*64, xcd*64+64);
  // 4 n-blocks of each m-panel consecutive -> same-XCD L2 reuse of A.
  const int bid = blockIdx.x;
  const int slot = bid >> 3;
  const int mblk = (bid & 7) * 64 + (slot >> 2);
  const int nblk = slot & 3;
  const int m0 = mblk * 128, n0 = nblk * 128;

  // B staging: chunk c covers row r = c*32 + (t>>3); 16B slot sb = t&7 (LDS linear,
  // global source pre-swizzled: LDS[r][s] = global[r][s^(r&7)]).
  const int rbb = t >> 3;
  const int sb = t & 7;
  // A staging (coalesced): step j -> row = j*16 + (t>>4), cols [(t&15)*4, +4) f32.
  const int rowA = t >> 4;          // 0..15
  // swizzled byte-in-row for the bf16 LDS write (row&7 == rowA&7 since j*16 % 8 == 0)
  const int wbyte = ((t & 15) * 8) ^ ((rowA & 7) << 4);

  const int l15 = lane & 15;
  const int lsl = lane >> 4;   // k sub-slot 0..3

  const float* aBase = latent + (size_t)(m0 + rowA) * D_MODEL + (t & 15) * 4;
  const short* bptr[4];
#pragma unroll
  for (int c = 0; c < 4; ++c) {
    const int r = c * 32 + rbb;
    const int sg = sb ^ (r & 7);
    bptr[c] = BT + (size_t)(n0 + r) * D_MODEL + sg * 8;
  }

  f32x4 acc[4][4] = {};
  f32x4 av0[8], av1[8];   // 2-deep A-tile prefetch registers (parity = tile index & 1)

  // ---- helpers (macros keep every LDS address compile-time static) ----
#define STAGE_B(KO, BDST)                                                   \
  {                                                                         \
    _Pragma("unroll") for (int c = 0; c < 4; ++c)                           \
        gload_lds16(bptr[c] + (KO), (char*)(BDST) + c * 4096 + t * 16);     \
  }
#define LOAD_A(KO, AV)                                                      \
  {                                                                         \
    _Pragma("unroll") for (int j = 0; j < 8; ++j)                           \
        (AV)[j] = *reinterpret_cast<const f32x4*>(aBase + (size_t)j * 16 * D_MODEL + (KO)); \
  }
#define WRITE_A(AV, ADST)                                                   \
  {                                                                         \
    _Pragma("unroll") for (int j = 0; j < 8; ++j) {                         \
      short4v h;                                                            \
      h[0] = f2bf((AV)[j][0]); h[1] = f2bf((AV)[j][1]);                     \
      h[2] = f2bf((AV)[j][2]); h[3] = f2bf((AV)[j][3]);                     \
      *reinterpret_cast<short4v*>((char*)(ADST) + (j * 16 + rowA) * 128 + wbyte) = h; \
    }                                                                       \
  }
#define COMPUTE(ASRC, BSRC)                                                 \
  {                                                                         \
    _Pragma("unroll") for (int kk = 0; kk < 2; ++kk) {                      \
      bf16x8 af[4], bfv[4];                                                 \
      _Pragma("unroll") for (int mi = 0; mi < 4; ++mi) {                    \
        const int r = wm * 64 + mi * 16 + l15;                              \
        const int s = (kk * 4 + lsl) ^ (r & 7);                             \
        af[mi] = as_bf16x8(                                                 \
            *reinterpret_cast<const short8*>((char*)(ASRC) + r * 128 + s * 16)); \
      }                                                                     \
      _Pragma("unroll") for (int ni = 0; ni < 4; ++ni) {                    \
        const int r = wn * 64 + ni * 16 + l15;                              \
        const int s = (kk * 4 + lsl) ^ (r & 7);                             \
        bfv[ni] = as_bf16x8(                                                \
            *reinterpret_cast<const short8*>((char*)(BSRC) + r * 128 + s * 16)); \
      }                                                                     \
      _Pragma("unroll") for (int mi = 0; mi < 4; ++mi)                      \
          _Pragma("unroll") for (int ni = 0; ni < 4; ++ni)                  \
              acc[mi][ni] = __builtin_amdgcn_mfma_f32_16x16x32_bf16(        \
                  af[mi], bfv[ni], acc[mi][ni], 0, 0, 0);                   \
    }                                                                       \
  }

  // ---- prologue: tiles 0,1 into regs; tile 0 into LDS buffer 0 ----
  LOAD_A(0, av0);
  LOAD_A(64, av1);
  STAGE_B(0, Bs0);
  WRITE_A(av0, As0);
  __syncthreads();

  // ---- main loop: 8 K-steps (tiles 0..7), fully unrolled, static buffers ----
#pragma unroll
  for (int tt = 0; tt < 8; ++tt) {
    short* Acur = (tt & 1) ? As1 : As0;
    short* Bcur = (tt & 1) ? Bs1 : Bs0;
    short* Anxt = (tt & 1) ? As0 : As1;
    short* Bnxt = (tt & 1) ? Bs0 : Bs1;
    // issue A-loads for tile tt+2 into the parity slot just freed (tile tt's regs
    // were consumed at step tt-1's WRITE_A)
    if (tt < 6) {
      f32x4(&ld)[8] = (tt & 1) ? av1 : av0;
      LOAD_A((tt + 2) * 64, ld);
    }
    // issue B-stage for tile tt+1
    if (tt < 7) STAGE_B((tt + 1) * 64, Bnxt);
    // compute tile tt from LDS
    COMPUTE(Acur, Bcur);
    // convert+write tile tt+1 (loaded one full step ago)
    if (tt < 7) {
      f32x4(&wr)[8] = (tt & 1) ? av0 : av1;
      WRITE_A(wr, Anxt);
      __syncthreads();
    }
  }

  // epilogue: fused gather of encW rows (2 MB, L2/L3-resident) + bias
#pragma unroll
  for (int mi = 0; mi < 4; ++mi) {
#pragma unroll
    for (int r = 0; r < 4; ++r) {
      const int row = m0 + wm * 64 + mi * 16 + lsl * 4 + r;
      const int d1 = dfn[row];
      const int d2 = dfa[row];
      const float* e1 = encW + (size_t)d1 * D_MODEL;
      const float* e2 = encW + (size_t)d2 * D_MODEL;
      const size_t ro = (size_t)row * D_MODEL;
#pragma unroll
      for (int ni = 0; ni < 4; ++ni) {
        const int col = n0 + wn * 64 + ni * 16 + l15;
        out[ro + col] = acc[mi][ni][r] + e1[col] + e2[col] + bias[col];
      }
    }
  }
#undef STAGE_B
#undef LOAD_A
#undef WRITE_A
#undef COMPUTE
}

extern "C" void kernel_launch(void* const* d_in, const int* in_sizes, int n_in,
                              void* d_out, int out_size, void* d_ws, size_t ws_size,
                              hipStream_t stream) {
  const int* dfn = (const int*)d_in[0];
  const int* dfa = (const int*)d_in[1];
  const float* latent = (const float*)d_in[2];
  const float* enc = (const float*)d_in[3];
  const float* W = (const float*)d_in[4];
  const float* bias = (const float*)d_in[5];
  float* out = (float*)d_out;

  // workspace layout (4 MB total)
  char* ws = (char*)d_ws;
  short* WtT  = (short*)(ws);                       // 512KB  [512][512] bf16
  short* WbT  = (short*)(ws + 512 * 1024);          // 512KB  [512][512] bf16
  short* encb = (short*)(ws + 1024 * 1024);         // 1MB    [1024][512] bf16
  float* encW = (float*)(ws + 2 * 1024 * 1024);     // 2MB    [1024][512] f32

  hipLaunchKernelGGL(prep_w_kernel, dim3(8, 16), dim3(256), 0, stream, W, WtT, WbT);
  hipLaunchKernelGGL(prep_enc_kernel, dim3(512), dim3(256), 0, stream, enc, encb);
  hipLaunchKernelGGL(gemm_encw_kernel, dim3(4, 8), dim3(256), 0, stream, encb, WtT, encW);
  hipLaunchKernelGGL(gemm_main_kernel, dim3(2048), dim3(256), 0, stream,
                     latent, WbT, encW, dfn, dfa, bias, out);
}